// Round 1
// baseline (1016.605 us; speedup 1.0000x reference)
//
#include <hip/hip_runtime.h>
#include <cstdint>

// Problem constants (B,S,IN,OUT) = (4,512,512,112)
constexpr int B_    = 4;
constexpr int S_    = 512;
constexpr int IN_   = 512;
constexpr int OUT_  = 112;
constexpr int NROW_ = B_ * S_;      // 2048 rows (b,x) or (b,y)
constexpr int NN_   = OUT_ * IN_;   // 57344 = GEMM1 N dim; also S_*OUT_ per-b GEMM2 N dim
constexpr int K_    = IN_;          // 512 reduction dim for both GEMMs

typedef __attribute__((ext_vector_type(8))) short          s16x8;  // 8 bf16 = 4 VGPR (MFMA A/B frag)
typedef __attribute__((ext_vector_type(4))) float          f32x4;  // MFMA C/D frag
typedef __attribute__((ext_vector_type(8))) unsigned short u16x8;
typedef __attribute__((ext_vector_type(4))) unsigned short u16x4;

// fp32 -> bf16, round-to-nearest-even
__device__ __forceinline__ unsigned short f2bf(float f) {
  union { float f; unsigned u; } v; v.f = f;
  unsigned u = v.u;
  return (unsigned short)((u + 0x7FFFu + ((u >> 16) & 1u)) >> 16);
}

// async global->LDS, 16B per lane. LDS dest is wave-uniform base + lane*16;
// our per-lane lds ptr is exactly base + lane*16 (rows of 64B, lane>>2 = row, lane&3 = 16B chunk).
__device__ __forceinline__ void gld_lds16(const void* g, void* l) {
  __builtin_amdgcn_global_load_lds(
      (const __attribute__((address_space(1))) unsigned int*)(unsigned long long)g,
      (__attribute__((address_space(3))) unsigned int*)(unsigned int)(unsigned long long)l,
      16, 0, 0);
}

// ---------------- kernel 1: cast input1/input2 to bf16 ----------------
__global__ __launch_bounds__(256) void cast_kernel(
    const float* __restrict__ in1, const float* __restrict__ in2,
    unsigned short* __restrict__ in1b, unsigned short* __restrict__ in2b) {
  int idx = blockIdx.x * 256 + threadIdx.x;          // 262144 float4's
  float4 v1 = ((const float4*)in1)[idx];
  float4 v2 = ((const float4*)in2)[idx];
  ((u16x4*)in1b)[idx] = (u16x4){f2bf(v1.x), f2bf(v1.y), f2bf(v1.z), f2bf(v1.w)};
  ((u16x4*)in2b)[idx] = (u16x4){f2bf(v2.x), f2bf(v2.y), f2bf(v2.z), f2bf(v2.w)};
}

// ---------------- kernel 2: w1 [i][n] fp32 -> w1T [n][i] bf16 ----------------
// tile: 32 i x 64 n, through LDS (row stride 40 shorts = 80B keeps 16B chunks aligned)
__global__ __launch_bounds__(256) void transpose_w1(
    const float* __restrict__ w1, unsigned short* __restrict__ w1T) {
  __shared__ unsigned short tile[64][40];
  const int t  = threadIdx.x;
  const int n0 = blockIdx.x * 64;
  const int i0 = blockIdx.y * 32;
#pragma unroll
  for (int p = 0; p < 8; ++p) {
    int il = p * 4 + (t >> 6);
    int nl = t & 63;
    tile[nl][il] = f2bf(w1[(size_t)(i0 + il) * NN_ + n0 + nl]);
  }
  __syncthreads();
  int nl = t >> 2, ch = t & 3;
  u16x8 v = *(const u16x8*)&tile[nl][ch * 8];
  *(u16x8*)&w1T[(size_t)(n0 + nl) * K_ + i0 + ch * 8] = v;
}

// ---------------- kernel 3: termA (incl. bias) / termB ----------------
// NOTE: reference computes termB from input1 (not input2) — replicated.
__global__ __launch_bounds__(128) void term_kernel(
    const float* __restrict__ in1, const float* __restrict__ w2,
    float* __restrict__ termA, float* __restrict__ termB) {
  const int bx = blockIdx.x;          // 0..2047
  const int o  = threadIdx.x;
  if (o >= OUT_) return;
  const float* row = in1 + (size_t)bx * IN_;
  float a = 0.f, c = 0.f;
  for (int i = 0; i < IN_; ++i) {
    float v = row[i];                  // uniform -> scalar load
    a += v * w2[i * OUT_ + o];
    c += v * w2[(IN_ + i) * OUT_ + o];
  }
  termA[bx * OUT_ + o] = a + w2[2 * IN_ * OUT_ + o];   // fold bias into termA
  termB[bx * OUT_ + o] = c;
}

// ---------------- kernel 4: GEMM1  U[bx][n=(o,j)] = in1b[bx][:] . w1T[n][:] ----------------
// M=2048(bx) N=57344 K=512, 128x128x32 tile, 4 waves (2x2), mfma 16x16x32 bf16.
// blockIdx.x = m-tile (16, fast) so concurrent blocks share w1T n-panels -> w1T read ~once from HBM.
__global__ __launch_bounds__(256) void gemm1_kernel(
    const unsigned short* __restrict__ A,   // in1b [2048][512]
    const unsigned short* __restrict__ Bm,  // w1T  [57344][512]
    unsigned short* __restrict__ U) {       // [2048][57344] bf16
  __shared__ unsigned short As[128 * 32];
  __shared__ unsigned short Bs[128 * 32];
  const int tid = threadIdx.x;
  const int wid = tid >> 6, lane = tid & 63;
  const int wm = wid & 1, wn = wid >> 1;
  const int m0 = blockIdx.x * 128;
  const int n0 = blockIdx.y * 128;
  const int rl0 = wid * 16 + (lane >> 2);
  const int rl1 = rl0 + 64;
  const int kcol = lane & 3;

  const unsigned short* aP0 = A + (size_t)(m0 + rl0) * K_ + kcol * 8;
  const unsigned short* aP1 = A + (size_t)(m0 + rl1) * K_ + kcol * 8;
  const unsigned short* bP0 = Bm + (size_t)(n0 + rl0) * K_ + kcol * 8;
  const unsigned short* bP1 = Bm + (size_t)(n0 + rl1) * K_ + kcol * 8;
  unsigned short* lA0 = &As[rl0 * 32 + kcol * 8];
  unsigned short* lA1 = &As[rl1 * 32 + kcol * 8];
  unsigned short* lB0 = &Bs[rl0 * 32 + kcol * 8];
  unsigned short* lB1 = &Bs[rl1 * 32 + kcol * 8];

  const int ln = lane & 15, q = lane >> 4;
  f32x4 acc[4][4];
#pragma unroll
  for (int i = 0; i < 4; ++i)
#pragma unroll
    for (int j = 0; j < 4; ++j) acc[i][j] = (f32x4){0.f, 0.f, 0.f, 0.f};

  for (int kt = 0; kt < K_ / 32; ++kt) {
    gld_lds16(aP0, lA0); gld_lds16(aP1, lA1);
    gld_lds16(bP0, lB0); gld_lds16(bP1, lB1);
    aP0 += 32; aP1 += 32; bP0 += 32; bP1 += 32;
    __syncthreads();                       // drains vmcnt(0) then barrier
    s16x8 af[4], bfr[4];
#pragma unroll
    for (int mf = 0; mf < 4; ++mf)
      af[mf] = *(const s16x8*)&As[(wm * 64 + mf * 16 + ln) * 32 + q * 8];
#pragma unroll
    for (int nf = 0; nf < 4; ++nf)
      bfr[nf] = *(const s16x8*)&Bs[(wn * 64 + nf * 16 + ln) * 32 + q * 8];
#pragma unroll
    for (int mf = 0; mf < 4; ++mf)
#pragma unroll
      for (int nf = 0; nf < 4; ++nf)
        acc[mf][nf] = __builtin_amdgcn_mfma_f32_16x16x32_bf16(af[mf], bfr[nf], acc[mf][nf], 0, 0, 0);
    __syncthreads();
  }
  // D layout: row m = q*4 + reg, col n = lane&15 (m89/m91-verified)
#pragma unroll
  for (int mf = 0; mf < 4; ++mf) {
    const int mrow = m0 + wm * 64 + mf * 16 + q * 4;
#pragma unroll
    for (int nf = 0; nf < 4; ++nf) {
      const int ncol = n0 + wn * 64 + nf * 16 + ln;
#pragma unroll
      for (int r = 0; r < 4; ++r)
        U[(size_t)(mrow + r) * NN_ + ncol] = f2bf(acc[mf][nf][r]);
    }
  }
}

// ---------------- kernel 5: GEMM2 + epilogue ----------------
// per b: out[y][(x,o)] = in2b[b][y][:] . U[b*512+x][o*512 .. +511]  + termA[b][x][o] + termB[b][y][o]
// A = in2b (m=y), B = U rows (n=(x,o)) -> D col = consecutive o -> coalesced fp32 stores.
__global__ __launch_bounds__(256) void gemm2_kernel(
    const unsigned short* __restrict__ A,   // in2b [4][512][512]
    const unsigned short* __restrict__ U,   // [4*512][112*512]
    const float* __restrict__ termA,        // [4][57344]  (bias folded in)
    const float* __restrict__ termB,        // [4][512][112]
    float* __restrict__ out) {              // [4][512][512][112]
  __shared__ unsigned short As[128 * 32];
  __shared__ unsigned short Bs[128 * 32];
  const int tid = threadIdx.x;
  const int wid = tid >> 6, lane = tid & 63;
  const int wm = wid & 1, wn = wid >> 1;
  const int b  = blockIdx.z;
  const int m0 = blockIdx.x * 128;   // y      (4 m-tiles, fast dim -> share U n-panels)
  const int n0 = blockIdx.y * 128;   // (x,o)  (448 n-tiles)
  const int rl0 = wid * 16 + (lane >> 2);
  const int rl1 = rl0 + 64;
  const int kcol = lane & 3;

  const unsigned short* aP0 = A + (size_t)(b * S_ + m0 + rl0) * K_ + kcol * 8;
  const unsigned short* aP1 = A + (size_t)(b * S_ + m0 + rl1) * K_ + kcol * 8;
  const int r2 = n0 + rl0, x0r = r2 / OUT_, o0r = r2 - x0r * OUT_;
  const int r3 = n0 + rl1, x1r = r3 / OUT_, o1r = r3 - x1r * OUT_;
  const unsigned short* bP0 = U + (size_t)(b * S_ + x0r) * NN_ + o0r * K_ + kcol * 8;
  const unsigned short* bP1 = U + (size_t)(b * S_ + x1r) * NN_ + o1r * K_ + kcol * 8;
  unsigned short* lA0 = &As[rl0 * 32 + kcol * 8];
  unsigned short* lA1 = &As[rl1 * 32 + kcol * 8];
  unsigned short* lB0 = &Bs[rl0 * 32 + kcol * 8];
  unsigned short* lB1 = &Bs[rl1 * 32 + kcol * 8];

  const int ln = lane & 15, q = lane >> 4;
  f32x4 acc[4][4];
#pragma unroll
  for (int i = 0; i < 4; ++i)
#pragma unroll
    for (int j = 0; j < 4; ++j) acc[i][j] = (f32x4){0.f, 0.f, 0.f, 0.f};

  for (int kt = 0; kt < K_ / 32; ++kt) {
    gld_lds16(aP0, lA0); gld_lds16(aP1, lA1);
    gld_lds16(bP0, lB0); gld_lds16(bP1, lB1);
    aP0 += 32; aP1 += 32; bP0 += 32; bP1 += 32;
    __syncthreads();
    s16x8 af[4], bfr[4];
#pragma unroll
    for (int mf = 0; mf < 4; ++mf)
      af[mf] = *(const s16x8*)&As[(wm * 64 + mf * 16 + ln) * 32 + q * 8];
#pragma unroll
    for (int nf = 0; nf < 4; ++nf)
      bfr[nf] = *(const s16x8*)&Bs[(wn * 64 + nf * 16 + ln) * 32 + q * 8];
#pragma unroll
    for (int mf = 0; mf < 4; ++mf)
#pragma unroll
      for (int nf = 0; nf < 4; ++nf)
        acc[mf][nf] = __builtin_amdgcn_mfma_f32_16x16x32_bf16(af[mf], bfr[nf], acc[mf][nf], 0, 0, 0);
    __syncthreads();
  }

#pragma unroll
  for (int nf = 0; nf < 4; ++nf) {
    const int n = n0 + wn * 64 + nf * 16 + ln;
    const int x = n / OUT_, o = n - x * OUT_;
    const float tA = termA[b * NN_ + n];
    const float* tB = termB + b * NN_ + o;
    float* op = out + ((size_t)(b * S_ + x) * S_) * OUT_ + o;
#pragma unroll
    for (int mf = 0; mf < 4; ++mf) {
      const int y0 = m0 + wm * 64 + mf * 16 + q * 4;
#pragma unroll
      for (int r = 0; r < 4; ++r) {
        const int y = y0 + r;
        op[(size_t)y * OUT_] = acc[mf][nf][r] + tA + tB[y * OUT_];
      }
    }
  }
}

extern "C" void kernel_launch(void* const* d_in, const int* in_sizes, int n_in,
                              void* d_out, int out_size, void* d_ws, size_t ws_size,
                              hipStream_t stream) {
  const float* in1 = (const float*)d_in[0];
  const float* in2 = (const float*)d_in[1];
  const float* w1  = (const float*)d_in[2];
  const float* w2  = (const float*)d_in[3];
  float* out = (float*)d_out;

  char* ws = (char*)d_ws;
  size_t off = 0;
  unsigned short* w1T  = (unsigned short*)(ws + off); off += (size_t)NN_ * K_ * 2;     //  58.7 MB
  unsigned short* U    = (unsigned short*)(ws + off); off += (size_t)NROW_ * NN_ * 2;  // 234.9 MB
  unsigned short* in1b = (unsigned short*)(ws + off); off += (size_t)NROW_ * IN_ * 2;  //   2.1 MB
  unsigned short* in2b = (unsigned short*)(ws + off); off += (size_t)NROW_ * IN_ * 2;  //   2.1 MB
  float* termA = (float*)(ws + off); off += (size_t)NROW_ * OUT_ * 4;                  //   0.9 MB
  float* termB = (float*)(ws + off); off += (size_t)NROW_ * OUT_ * 4;                  //   0.9 MB
  if (ws_size < off) return;  // diagnostic: absmax will read exactly 136 (= max|ref|) if ws too small

  cast_kernel<<<(NROW_ * IN_ / 4) / 256, 256, 0, stream>>>(in1, in2, in1b, in2b);
  transpose_w1<<<dim3(NN_ / 64, K_ / 32), 256, 0, stream>>>(w1, w1T);
  term_kernel<<<NROW_, 128, 0, stream>>>(in1, w2, termA, termB);
  gemm1_kernel<<<dim3(NROW_ / 128, NN_ / 128), 256, 0, stream>>>(in1b, w1T, U);
  gemm2_kernel<<<dim3(S_ / 128, NN_ / 128, B_), 256, 0, stream>>>(in2b, U, termA, termB, out);
}